// Round 1
// baseline (808.530 us; speedup 1.0000x reference)
//
#include <hip/hip_runtime.h>
#include <math.h>

// Problem constants (from reference): B=4, SQ=SP=2048, H=256
#define BB 4
#define SS 2048
#define HH 256
#define NEG_BIG -1e9f
#define GSEG ((size_t)BB * SS * 5 * HH)  // elements per output tensor

// ------------------------------------------------------------------
// K0: sp[b,p] = dot(E_p[b,p,:], w_p);  sq[b,q] = dot(E_q[b,q,:], w_q)
// one wave (64 lanes) per row; lane loads float4 (64*4 = 256 = H)
// ------------------------------------------------------------------
__global__ __launch_bounds__(256) void k_rowdots(
    const float* __restrict__ Eq, const float* __restrict__ Ep,
    const float* __restrict__ W,
    float* __restrict__ sqv, float* __restrict__ spv) {
  int g = blockIdx.x * 256 + threadIdx.x;
  int wid = g >> 6;
  int lane = g & 63;
  const int total = BB * SS;
  int isp = wid >= total;
  int row = isp ? (wid - total) : wid;
  const float* Er = (isp ? Ep : Eq) + (size_t)row * HH;
  const float* w = W + (isp ? HH : 0);
  float4 e = ((const float4*)Er)[lane];
  float4 wv = ((const float4*)w)[lane];
  float acc = e.x * wv.x + e.y * wv.y + e.z * wv.z + e.w * wv.w;
#pragma unroll
  for (int off = 32; off > 0; off >>= 1) acc += __shfl_down(acc, off, 64);
  if (lane == 0) (isp ? spv : sqv)[row] = acc;
}

// ------------------------------------------------------------------
// K1: U[b,p,q] = dot(E_p[b,p,:]*w_m, E_q[b,q,:]) + sp[b,p] + sq[b,q], masked
// 64x64 tile, K=256 in 32-chunks, 256 thr, 4x4 micro, k-major LDS (pad 68)
// ------------------------------------------------------------------
__global__ __launch_bounds__(256) void k_tri(
    const float* __restrict__ Eq, const float* __restrict__ Ep,
    const float* __restrict__ W,
    const float* __restrict__ m1, const float* __restrict__ m2,
    const float* __restrict__ spv, const float* __restrict__ sqv,
    float* __restrict__ U) {
  alignas(16) __shared__ float As[32][68];
  alignas(16) __shared__ float Bs[32][68];
  int b = blockIdx.z;
  int q0 = blockIdx.x << 6;
  int p0 = blockIdx.y << 6;
  int tid = threadIdx.x;
  int tx = tid & 15, ty = tid >> 4;
  size_t bS = (size_t)b * SS;
  const float* EpB = Ep + bS * HH;
  const float* EqB = Eq + bS * HH;
  const float* wm = W + 2 * HH;
  float acc[4][4] = {};
  for (int k0 = 0; k0 < HH; k0 += 32) {
#pragma unroll
    for (int i = 0; i < 2; ++i) {
      int idx = tid + i * 256;
      int r = idx >> 3;
      int c4 = (idx & 7) << 2;
      float4 w4 = *(const float4*)(wm + k0 + c4);
      float4 a4 = *(const float4*)(EpB + (size_t)(p0 + r) * HH + k0 + c4);
      float4 b4 = *(const float4*)(EqB + (size_t)(q0 + r) * HH + k0 + c4);
      As[c4 + 0][r] = a4.x * w4.x;
      As[c4 + 1][r] = a4.y * w4.y;
      As[c4 + 2][r] = a4.z * w4.z;
      As[c4 + 3][r] = a4.w * w4.w;
      Bs[c4 + 0][r] = b4.x;
      Bs[c4 + 1][r] = b4.y;
      Bs[c4 + 2][r] = b4.z;
      Bs[c4 + 3][r] = b4.w;
    }
    __syncthreads();
#pragma unroll
    for (int k = 0; k < 32; ++k) {
      float4 a4 = *(const float4*)&As[k][ty << 2];
      float4 b4 = *(const float4*)&Bs[k][tx << 2];
      acc[0][0] += a4.x * b4.x; acc[0][1] += a4.x * b4.y; acc[0][2] += a4.x * b4.z; acc[0][3] += a4.x * b4.w;
      acc[1][0] += a4.y * b4.x; acc[1][1] += a4.y * b4.y; acc[1][2] += a4.y * b4.z; acc[1][3] += a4.y * b4.w;
      acc[2][0] += a4.z * b4.x; acc[2][1] += a4.z * b4.y; acc[2][2] += a4.z * b4.z; acc[2][3] += a4.z * b4.w;
      acc[3][0] += a4.w * b4.x; acc[3][1] += a4.w * b4.y; acc[3][2] += a4.w * b4.z; acc[3][3] += a4.w * b4.w;
    }
    __syncthreads();
  }
  int prow = p0 + (ty << 2);
  int qcol = q0 + (tx << 2);
  float spr[4], mpr[4], sqc[4], mqc[4];
#pragma unroll
  for (int i = 0; i < 4; ++i) { spr[i] = spv[bS + prow + i]; mpr[i] = m1[bS + prow + i]; }
#pragma unroll
  for (int j = 0; j < 4; ++j) { sqc[j] = sqv[bS + qcol + j]; mqc[j] = m2[bS + qcol + j]; }
#pragma unroll
  for (int i = 0; i < 4; ++i) {
    float4 o;
    o.x = (mpr[i] * mqc[0] < 0.5f) ? NEG_BIG : (acc[i][0] + spr[i] + sqc[0]);
    o.y = (mpr[i] * mqc[1] < 0.5f) ? NEG_BIG : (acc[i][1] + spr[i] + sqc[1]);
    o.z = (mpr[i] * mqc[2] < 0.5f) ? NEG_BIG : (acc[i][2] + spr[i] + sqc[2]);
    o.w = (mpr[i] * mqc[3] < 0.5f) ? NEG_BIG : (acc[i][3] + spr[i] + sqc[3]);
    *(float4*)(U + (bS + prow + i) * SS + qcol) = o;
  }
}

// ------------------------------------------------------------------
// K2: row softmax stats (axis=2, over q). one block per (b,p) row.
// ------------------------------------------------------------------
__global__ __launch_bounds__(256) void k_rowstats(
    const float* __restrict__ U, float* __restrict__ rowmax, float* __restrict__ rowinv) {
  __shared__ float redm[4];
  __shared__ float reds[4];
  int row = blockIdx.x;
  int tid = threadIdx.x;
  const float* u = U + (size_t)row * SS;
  float4 v1 = ((const float4*)u)[tid];
  float4 v2 = ((const float4*)u)[tid + 256];
  float m = fmaxf(fmaxf(fmaxf(v1.x, v1.y), fmaxf(v1.z, v1.w)),
                  fmaxf(fmaxf(v2.x, v2.y), fmaxf(v2.z, v2.w)));
#pragma unroll
  for (int off = 32; off > 0; off >>= 1) m = fmaxf(m, __shfl_down(m, off, 64));
  if ((tid & 63) == 0) redm[tid >> 6] = m;
  __syncthreads();
  m = fmaxf(fmaxf(redm[0], redm[1]), fmaxf(redm[2], redm[3]));
  float s = __expf(v1.x - m) + __expf(v1.y - m) + __expf(v1.z - m) + __expf(v1.w - m)
          + __expf(v2.x - m) + __expf(v2.y - m) + __expf(v2.z - m) + __expf(v2.w - m);
#pragma unroll
  for (int off = 32; off > 0; off >>= 1) s += __shfl_down(s, off, 64);
  if ((tid & 63) == 0) reds[tid >> 6] = s;
  __syncthreads();
  if (tid == 0) {
    float st = reds[0] + reds[1] + reds[2] + reds[3];
    rowmax[row] = m;
    rowinv[row] = 1.0f / st;
  }
}

// ------------------------------------------------------------------
// K3a: column softmax stats (axis=1, over p), partial over 128-p chunks.
// thread owns one column q; online max/sum. coalesced 1KB reads per step.
// ------------------------------------------------------------------
__global__ __launch_bounds__(256) void k_colpart(
    const float* __restrict__ U, float* __restrict__ pm, float* __restrict__ ps) {
  int q = blockIdx.x * 256 + threadIdx.x;
  int pc = blockIdx.y;
  int b = blockIdx.z;
  const float* u = U + ((size_t)b * SS + pc * 128) * SS + q;
  float m = -INFINITY, s = 0.f;
  for (int p = 0; p < 128; ++p) {
    float x = u[(size_t)p * SS];
    float nm = fmaxf(m, x);
    s = s * __expf(m - nm) + __expf(x - nm);
    m = nm;
  }
  int o = (pc * BB + b) * SS + q;
  pm[o] = m;
  ps[o] = s;
}

// K3b: combine 16 partials per (b,q)
__global__ __launch_bounds__(256) void k_colcomb(
    const float* __restrict__ pm, const float* __restrict__ ps,
    float* __restrict__ colmax, float* __restrict__ colinv) {
  int i = blockIdx.x * 256 + threadIdx.x;  // i = b*SS + q
  float m = -INFINITY;
#pragma unroll
  for (int pc = 0; pc < 16; ++pc) m = fmaxf(m, pm[(size_t)pc * BB * SS + i]);
  float s = 0.f;
#pragma unroll
  for (int pc = 0; pc < 16; ++pc)
    s += ps[(size_t)pc * BB * SS + i] * __expf(pm[(size_t)pc * BB * SS + i] - m);
  colmax[i] = m;
  colinv[i] = 1.0f / s;
}

// ------------------------------------------------------------------
// Shared GEMM core for levels 1/2:
//   mode 0: out rows = p, Ps[k=q][r=p] = exp(U[p,q]-rowmax[p]),  B-op rows q
//   mode 1: out rows = q, Ps[k=p][r=q] = exp(U[p,q]-colmax[q]),  B-op rows p
// 32 out-rows x 256 out-cols per block; micro 4 rows x 8 (stride-32) cols.
// ------------------------------------------------------------------
__device__ __forceinline__ void gemm_core(
    const float* __restrict__ Ub, const float* __restrict__ Esrc,
    const float* __restrict__ rowmax, const float* __restrict__ colmax,
    int mode, int r0, size_t bS, int tid,
    float (&Ps)[32][36], float (&Es)[32][256], float acc[4][8]) {
  int tx = tid & 31, ty = tid >> 5;
  for (int k0 = 0; k0 < SS; k0 += 32) {
    {
      int r = tid >> 3;
      int c4 = (tid & 7) << 2;
      if (mode == 0) {
        float4 u4 = *(const float4*)(Ub + (size_t)(r0 + r) * SS + k0 + c4);
        float rm = rowmax[bS + r0 + r];
        Ps[c4 + 0][r] = __expf(u4.x - rm);
        Ps[c4 + 1][r] = __expf(u4.y - rm);
        Ps[c4 + 2][r] = __expf(u4.z - rm);
        Ps[c4 + 3][r] = __expf(u4.w - rm);
      } else {
        float4 u4 = *(const float4*)(Ub + (size_t)(k0 + r) * SS + r0 + c4);
        float4 cm = *(const float4*)(colmax + bS + r0 + c4);
        Ps[r][c4 + 0] = __expf(u4.x - cm.x);
        Ps[r][c4 + 1] = __expf(u4.y - cm.y);
        Ps[r][c4 + 2] = __expf(u4.z - cm.z);
        Ps[r][c4 + 3] = __expf(u4.w - cm.w);
      }
    }
#pragma unroll
    for (int i = 0; i < 8; ++i) {
      int idx = tid + i * 256;
      int rr = idx >> 6;
      int c4 = (idx & 63) << 2;
      *(float4*)&Es[rr][c4] = *(const float4*)(Esrc + (size_t)(k0 + rr) * HH + c4);
    }
    __syncthreads();
#pragma unroll
    for (int k = 0; k < 32; ++k) {
      float4 a4 = *(const float4*)&Ps[k][ty << 2];
#pragma unroll
      for (int j = 0; j < 8; ++j) {
        float bv = Es[k][tx + 32 * j];
        acc[0][j] += a4.x * bv;
        acc[1][j] += a4.y * bv;
        acc[2][j] += a4.z * bv;
        acc[3][j] += a4.w * bv;
      }
    }
    __syncthreads();
  }
}

// K4: A1 (mode 0) / B1 (mode 1) into workspace
__global__ __launch_bounds__(256) void k_level1(
    const float* __restrict__ U,
    const float* __restrict__ Eq, const float* __restrict__ Ep,
    const float* __restrict__ rowmax, const float* __restrict__ rowinv,
    const float* __restrict__ colmax, const float* __restrict__ colinv,
    float* __restrict__ A1w, float* __restrict__ B1w) {
  alignas(16) __shared__ float Ps[32][36];
  alignas(16) __shared__ float Es[32][256];
  int b = blockIdx.z;
  int mode = blockIdx.y;
  int r0 = blockIdx.x << 5;
  int tid = threadIdx.x;
  size_t bS = (size_t)b * SS;
  const float* Ub = U + bS * SS;
  const float* Esrc = (mode == 0 ? Eq : Ep) + bS * HH;
  float acc[4][8] = {};
  gemm_core(Ub, Esrc, rowmax, colmax, mode, r0, bS, tid, Ps, Es, acc);
  int tx = tid & 31, ty = tid >> 5;
  const float* inv = (mode == 0 ? rowinv : colinv);
  float* Out = (mode == 0 ? A1w : B1w);
#pragma unroll
  for (int i = 0; i < 4; ++i) {
    int rr = r0 + (ty << 2) + i;
    float sc = inv[bS + rr];
#pragma unroll
    for (int j = 0; j < 8; ++j)
      Out[(bS + rr) * HH + tx + 32 * j] = acc[i][j] * sc;
  }
}

// K5: A2 (mode 0) / B2 (mode 1); epilogue writes all 5 concat segments.
// d_out = [G_p_q (B,SQ,5H) | G_q_p (B,SP,5H)]
__global__ __launch_bounds__(256) void k_level2(
    const float* __restrict__ U,
    const float* __restrict__ Eq, const float* __restrict__ Ep,
    const float* __restrict__ A1w, const float* __restrict__ B1w,
    const float* __restrict__ rowmax, const float* __restrict__ rowinv,
    const float* __restrict__ colmax, const float* __restrict__ colinv,
    float* __restrict__ out) {
  alignas(16) __shared__ float Ps[32][36];
  alignas(16) __shared__ float Es[32][256];
  int b = blockIdx.z;
  int mode = blockIdx.y;
  int r0 = blockIdx.x << 5;
  int tid = threadIdx.x;
  size_t bS = (size_t)b * SS;
  const float* Ub = U + bS * SS;
  const float* Esrc = (mode == 0 ? B1w : A1w) + bS * HH;  // A2 = A_p @ B1 ; B2 = B_p^T @ A1
  float acc[4][8] = {};
  gemm_core(Ub, Esrc, rowmax, colmax, mode, r0, bS, tid, Ps, Es, acc);
  int tx = tid & 31, ty = tid >> 5;
  if (mode == 0) {
    // rows are p -> G_q_p[b,p] = [E_p, A1, A2, E_p*A1, E_p*A2]
    float* Gqp = out + GSEG;
#pragma unroll
    for (int i = 0; i < 4; ++i) {
      int rr = r0 + (ty << 2) + i;
      float sc = rowinv[bS + rr];
#pragma unroll
      for (int j = 0; j < 8; ++j) {
        int h = tx + 32 * j;
        size_t eidx = (bS + rr) * HH + h;
        float a2 = acc[i][j] * sc;
        float ep = Ep[eidx];
        float a1 = A1w[eidx];
        float* g = Gqp + (bS + rr) * (5 * HH) + h;
        g[0 * HH] = ep;
        g[1 * HH] = a1;
        g[2 * HH] = a2;
        g[3 * HH] = ep * a1;
        g[4 * HH] = ep * a2;
      }
    }
  } else {
    // rows are q -> G_p_q[b,q] = [E_q, B1, B2, E_q*B1, E_q*B2]
#pragma unroll
    for (int i = 0; i < 4; ++i) {
      int rr = r0 + (ty << 2) + i;
      float sc = colinv[bS + rr];
#pragma unroll
      for (int j = 0; j < 8; ++j) {
        int h = tx + 32 * j;
        size_t eidx = (bS + rr) * HH + h;
        float b2 = acc[i][j] * sc;
        float eq = Eq[eidx];
        float b1 = B1w[eidx];
        float* g = out + (bS + rr) * (5 * HH) + h;
        g[0 * HH] = eq;
        g[1 * HH] = b1;
        g[2 * HH] = b2;
        g[3 * HH] = eq * b1;
        g[4 * HH] = eq * b2;
      }
    }
  }
}

// ------------------------------------------------------------------
extern "C" void kernel_launch(void* const* d_in, const int* in_sizes, int n_in,
                              void* d_out, int out_size, void* d_ws, size_t ws_size,
                              hipStream_t stream) {
  const float* Eq = (const float*)d_in[0];  // encode_input1 (B,SQ,H)
  const float* Ep = (const float*)d_in[1];  // encode_input2 (B,SP,H)
  const float* m1 = (const float*)d_in[2];  // input1_mask (B,SP)
  const float* m2 = (const float*)d_in[3];  // input2_mask (B,SQ)
  const float* W  = (const float*)d_in[4];  // (3H,)
  float* out = (float*)d_out;

  // workspace layout (floats): ~81.2 MiB total
  float* ws     = (float*)d_ws;
  float* U      = ws;                              // B*S*S
  float* rowmax = U + (size_t)BB * SS * SS;        // B*S
  float* rowinv = rowmax + BB * SS;
  float* colmax = rowinv + BB * SS;
  float* colinv = colmax + BB * SS;
  float* spv    = colinv + BB * SS;
  float* sqv    = spv + BB * SS;
  float* A1w    = sqv + BB * SS;                   // B*S*H
  float* B1w    = A1w + (size_t)BB * SS * HH;      // B*S*H
  float* pm     = B1w + (size_t)BB * SS * HH;      // 16*B*S
  float* ps     = pm + 16 * BB * SS;               // 16*B*S

  k_rowdots<<<2 * BB * SS / 4, 256, 0, stream>>>(Eq, Ep, W, sqv, spv);
  k_tri<<<dim3(SS / 64, SS / 64, BB), 256, 0, stream>>>(Eq, Ep, W, m1, m2, spv, sqv, U);
  k_rowstats<<<BB * SS, 256, 0, stream>>>(U, rowmax, rowinv);
  k_colpart<<<dim3(SS / 256, 16, BB), 256, 0, stream>>>(U, pm, ps);
  k_colcomb<<<BB * SS / 256, 256, 0, stream>>>(pm, ps, colmax, colinv);
  k_level1<<<dim3(SS / 32, 2, BB), 256, 0, stream>>>(U, Eq, Ep, rowmax, rowinv, colmax, colinv, A1w, B1w);
  k_level2<<<dim3(SS / 32, 2, BB), 256, 0, stream>>>(U, Eq, Ep, A1w, B1w, rowmax, rowinv, colmax, colinv, out);
}

// Round 3
// 799.340 us; speedup vs baseline: 1.0115x; 1.0115x over previous
//
#include <hip/hip_runtime.h>
#include <math.h>

// Problem constants (from reference): B=4, SQ=SP=2048, H=256
#define BB 4
#define SS 2048
#define HH 256
#define NEG_BIG -1e9f
#define GSEG ((size_t)BB * SS * 5 * HH)  // elements per output tensor
#define NT ((size_t)BB * SS * HH)        // elements per E-like tensor

typedef unsigned short ushort_t;
typedef __attribute__((ext_vector_type(8))) __bf16 bf16x8;
typedef __attribute__((ext_vector_type(4))) float f32x4;

// split fp32 into bf16 hi + bf16 lo (RNE both)
__device__ __forceinline__ void bsplit(float x, ushort_t& hi, ushort_t& lo) {
  union { float f; unsigned u; } a; a.f = x;
  unsigned r = a.u + 0x7FFFu + ((a.u >> 16) & 1u);
  ushort_t h = (ushort_t)(r >> 16);
  union { unsigned u; float f; } hf; hf.u = ((unsigned)h) << 16;
  float l = x - hf.f;
  union { float f; unsigned u; } b; b.f = l;
  unsigned r2 = b.u + 0x7FFFu + ((b.u >> 16) & 1u);
  hi = h; lo = (ushort_t)(r2 >> 16);
}

// ------------------------------------------------------------------
// K0: sp[b,p] = dot(E_p[b,p,:], w_p);  sq[b,q] = dot(E_q[b,q,:], w_q)
// ------------------------------------------------------------------
__global__ __launch_bounds__(256) void k_rowdots(
    const float* __restrict__ Eq, const float* __restrict__ Ep,
    const float* __restrict__ W,
    float* __restrict__ sqv, float* __restrict__ spv) {
  int g = blockIdx.x * 256 + threadIdx.x;
  int wid = g >> 6;
  int lane = g & 63;
  const int total = BB * SS;
  int isp = wid >= total;
  int row = isp ? (wid - total) : wid;
  const float* Er = (isp ? Ep : Eq) + (size_t)row * HH;
  const float* w = W + (isp ? HH : 0);
  float4 e = ((const float4*)Er)[lane];
  float4 wv = ((const float4*)w)[lane];
  float acc = e.x * wv.x + e.y * wv.y + e.z * wv.z + e.w * wv.w;
#pragma unroll
  for (int off = 32; off > 0; off >>= 1) acc += __shfl_down(acc, off, 64);
  if (lane == 0) (isp ? spv : sqv)[row] = acc;
}

// ------------------------------------------------------------------
// K_tc: transpose-convert  src fp32 [b][r<SS][h<HH]  ->  dhi/dlo bf16 [b][h][r]
// 64x64 tiles via LDS
// ------------------------------------------------------------------
__global__ __launch_bounds__(256) void k_tc(
    const float* __restrict__ src, ushort_t* __restrict__ dhi, ushort_t* __restrict__ dlo) {
  __shared__ float tile[64][65];
  int b = blockIdx.z;
  int r0 = blockIdx.x << 6;
  int h0 = blockIdx.y << 6;
  int tid = threadIdx.x;
  int rl = tid >> 4, c4 = (tid & 15) << 2;
  size_t srcb = (size_t)b * SS * HH;
#pragma unroll
  for (int i = 0; i < 4; ++i) {
    float4 v = *(const float4*)(src + srcb + (size_t)(r0 + rl + 16 * i) * HH + h0 + c4);
    tile[rl + 16 * i][c4 + 0] = v.x;
    tile[rl + 16 * i][c4 + 1] = v.y;
    tile[rl + 16 * i][c4 + 2] = v.z;
    tile[rl + 16 * i][c4 + 3] = v.w;
  }
  __syncthreads();
  size_t dstb = (size_t)b * HH;
#pragma unroll
  for (int i = 0; i < 4; ++i) {
    int h = rl + 16 * i;
    ushort4 h4, l4;
    ushort_t hh, ll;
    bsplit(tile[c4 + 0][h], hh, ll); h4.x = hh; l4.x = ll;
    bsplit(tile[c4 + 1][h], hh, ll); h4.y = hh; l4.y = ll;
    bsplit(tile[c4 + 2][h], hh, ll); h4.z = hh; l4.z = ll;
    bsplit(tile[c4 + 3][h], hh, ll); h4.w = hh; l4.w = ll;
    size_t o = (dstb + h0 + h) * SS + r0 + c4;
    *(ushort4*)(dhi + o) = h4;
    *(ushort4*)(dlo + o) = l4;
  }
}

// ------------------------------------------------------------------
// K1: U[b,p,q] = dot(E_p[b,p,:]*w_m, E_q[b,q,:]) + sp + sq, masked (fp32)
// ------------------------------------------------------------------
__global__ __launch_bounds__(256) void k_tri(
    const float* __restrict__ Eq, const float* __restrict__ Ep,
    const float* __restrict__ W,
    const float* __restrict__ m1, const float* __restrict__ m2,
    const float* __restrict__ spv, const float* __restrict__ sqv,
    float* __restrict__ U) {
  alignas(16) __shared__ float As[32][68];
  alignas(16) __shared__ float Bs[32][68];
  int b = blockIdx.z;
  int q0 = blockIdx.x << 6;
  int p0 = blockIdx.y << 6;
  int tid = threadIdx.x;
  int tx = tid & 15, ty = tid >> 4;
  size_t bS = (size_t)b * SS;
  const float* EpB = Ep + bS * HH;
  const float* EqB = Eq + bS * HH;
  const float* wm = W + 2 * HH;
  float acc[4][4] = {};
  for (int k0 = 0; k0 < HH; k0 += 32) {
#pragma unroll
    for (int i = 0; i < 2; ++i) {
      int idx = tid + i * 256;
      int r = idx >> 3;
      int c4 = (idx & 7) << 2;
      float4 w4 = *(const float4*)(wm + k0 + c4);
      float4 a4 = *(const float4*)(EpB + (size_t)(p0 + r) * HH + k0 + c4);
      float4 b4 = *(const float4*)(EqB + (size_t)(q0 + r) * HH + k0 + c4);
      As[c4 + 0][r] = a4.x * w4.x;
      As[c4 + 1][r] = a4.y * w4.y;
      As[c4 + 2][r] = a4.z * w4.z;
      As[c4 + 3][r] = a4.w * w4.w;
      Bs[c4 + 0][r] = b4.x;
      Bs[c4 + 1][r] = b4.y;
      Bs[c4 + 2][r] = b4.z;
      Bs[c4 + 3][r] = b4.w;
    }
    __syncthreads();
#pragma unroll
    for (int k = 0; k < 32; ++k) {
      float4 a4 = *(const float4*)&As[k][ty << 2];
      float4 b4 = *(const float4*)&Bs[k][tx << 2];
      acc[0][0] += a4.x * b4.x; acc[0][1] += a4.x * b4.y; acc[0][2] += a4.x * b4.z; acc[0][3] += a4.x * b4.w;
      acc[1][0] += a4.y * b4.x; acc[1][1] += a4.y * b4.y; acc[1][2] += a4.y * b4.z; acc[1][3] += a4.y * b4.w;
      acc[2][0] += a4.z * b4.x; acc[2][1] += a4.z * b4.y; acc[2][2] += a4.z * b4.z; acc[2][3] += a4.z * b4.w;
      acc[3][0] += a4.w * b4.x; acc[3][1] += a4.w * b4.y; acc[3][2] += a4.w * b4.z; acc[3][3] += a4.w * b4.w;
    }
    __syncthreads();
  }
  int prow = p0 + (ty << 2);
  int qcol = q0 + (tx << 2);
  float spr[4], mpr[4], sqc[4], mqc[4];
#pragma unroll
  for (int i = 0; i < 4; ++i) { spr[i] = spv[bS + prow + i]; mpr[i] = m1[bS + prow + i]; }
#pragma unroll
  for (int j = 0; j < 4; ++j) { sqc[j] = sqv[bS + qcol + j]; mqc[j] = m2[bS + qcol + j]; }
#pragma unroll
  for (int i = 0; i < 4; ++i) {
    float4 o;
    o.x = (mpr[i] * mqc[0] < 0.5f) ? NEG_BIG : (acc[i][0] + spr[i] + sqc[0]);
    o.y = (mpr[i] * mqc[1] < 0.5f) ? NEG_BIG : (acc[i][1] + spr[i] + sqc[1]);
    o.z = (mpr[i] * mqc[2] < 0.5f) ? NEG_BIG : (acc[i][2] + spr[i] + sqc[2]);
    o.w = (mpr[i] * mqc[3] < 0.5f) ? NEG_BIG : (acc[i][3] + spr[i] + sqc[3]);
    *(float4*)(U + (bS + prow + i) * SS + qcol) = o;
  }
}

// ------------------------------------------------------------------
// K2: row softmax stats (axis=2, over q)
// ------------------------------------------------------------------
__global__ __launch_bounds__(256) void k_rowstats(
    const float* __restrict__ U, float* __restrict__ rowmax, float* __restrict__ rowinv) {
  __shared__ float redm[4];
  __shared__ float reds[4];
  int row = blockIdx.x;
  int tid = threadIdx.x;
  const float* u = U + (size_t)row * SS;
  float4 v1 = ((const float4*)u)[tid];
  float4 v2 = ((const float4*)u)[tid + 256];
  float m = fmaxf(fmaxf(fmaxf(v1.x, v1.y), fmaxf(v1.z, v1.w)),
                  fmaxf(fmaxf(v2.x, v2.y), fmaxf(v2.z, v2.w)));
#pragma unroll
  for (int off = 32; off > 0; off >>= 1) m = fmaxf(m, __shfl_down(m, off, 64));
  if ((tid & 63) == 0) redm[tid >> 6] = m;
  __syncthreads();
  m = fmaxf(fmaxf(redm[0], redm[1]), fmaxf(redm[2], redm[3]));
  float s = __expf(v1.x - m) + __expf(v1.y - m) + __expf(v1.z - m) + __expf(v1.w - m)
          + __expf(v2.x - m) + __expf(v2.y - m) + __expf(v2.z - m) + __expf(v2.w - m);
#pragma unroll
  for (int off = 32; off > 0; off >>= 1) s += __shfl_down(s, off, 64);
  if ((tid & 63) == 0) reds[tid >> 6] = s;
  __syncthreads();
  if (tid == 0) {
    float st = reds[0] + reds[1] + reds[2] + reds[3];
    rowmax[row] = m;
    rowinv[row] = 1.0f / st;
  }
}

// ------------------------------------------------------------------
// K3a/K3b: column softmax stats (axis=1, over p)
// ------------------------------------------------------------------
__global__ __launch_bounds__(256) void k_colpart(
    const float* __restrict__ U, float* __restrict__ pm, float* __restrict__ ps) {
  int q = blockIdx.x * 256 + threadIdx.x;
  int pc = blockIdx.y;
  int b = blockIdx.z;
  const float* u = U + ((size_t)b * SS + pc * 128) * SS + q;
  float m = -INFINITY, s = 0.f;
  for (int p = 0; p < 128; ++p) {
    float x = u[(size_t)p * SS];
    float nm = fmaxf(m, x);
    s = s * __expf(m - nm) + __expf(x - nm);
    m = nm;
  }
  int o = (pc * BB + b) * SS + q;
  pm[o] = m;
  ps[o] = s;
}

__global__ __launch_bounds__(256) void k_colcomb(
    const float* __restrict__ pm, const float* __restrict__ ps,
    float* __restrict__ colmax, float* __restrict__ colinv) {
  int i = blockIdx.x * 256 + threadIdx.x;
  float m = -INFINITY;
#pragma unroll
  for (int pc = 0; pc < 16; ++pc) m = fmaxf(m, pm[(size_t)pc * BB * SS + i]);
  float s = 0.f;
#pragma unroll
  for (int pc = 0; pc < 16; ++pc)
    s += ps[(size_t)pc * BB * SS + i] * __expf(pm[(size_t)pc * BB * SS + i] - m);
  colmax[i] = m;
  colinv[i] = 1.0f / s;
}

// ------------------------------------------------------------------
// MFMA level kernels: Out[r,h] = sum_k exp(U - max) * E[k,h]
// split-bf16 3-MFMA (PhEh + PhEl + PlEh) = fp32-level accuracy.
// Block: 1024 thr = 16 waves (4x4), tile 64 rows x 256 h, BK=64.
// mode 0: rows=p, k=q, P = exp(U[p,q]-rowmax[p])       (A_p direction)
// mode 1: rows=q, k=p, P = exp(U[p,q]-colmax[q])       (B_p direction)
// B-operand read directly from global transposed bf16 [b][h][k].
// ------------------------------------------------------------------
template <int LEVEL>
__global__ __launch_bounds__(1024, 4) void k_level(
    const float* __restrict__ U,
    const ushort_t* __restrict__ B0h, const ushort_t* __restrict__ B0l,  // mode0 B^T
    const ushort_t* __restrict__ B1h, const ushort_t* __restrict__ B1l,  // mode1 B^T
    const float* __restrict__ rowmax, const float* __restrict__ rowinv,
    const float* __restrict__ colmax, const float* __restrict__ colinv,
    const float* __restrict__ Eq, const float* __restrict__ Ep,
    float* __restrict__ A1w, float* __restrict__ B1w,
    float* __restrict__ out) {
  __shared__ ushort_t Ph[64 * 64];
  __shared__ ushort_t Pl[64 * 64];
  int b = blockIdx.z;
  int mode = blockIdx.y;
  int r0 = blockIdx.x << 6;
  int tid = threadIdx.x;
  size_t bS = (size_t)b * SS;
  const float* Ub = U + bS * SS;
  const ushort_t* Bh = mode == 0 ? B0h : B1h;
  const ushort_t* Bl = mode == 0 ? B0l : B1l;

  // staging indices (fixed per thread)
  int srow = tid >> 4;            // 0..63
  int sc4 = (tid & 15) << 2;      // 0..60
  float rm = 0.f;
  float4 cm4;
  if (mode == 0) {
    rm = rowmax[bS + r0 + srow];
  } else {
    cm4 = *(const float4*)(colmax + bS + r0 + sc4);
  }

  // wave / fragment indices
  int w = tid >> 6, l = tid & 63;
  int wr = w >> 2, wc = w & 3;          // wave row/col group
  int arow = wr * 16 + (l & 15);        // A-frag row (local)
  unsigned arow_sw = ((unsigned)(arow & 7)) << 4;
  int lk8 = (l >> 4) << 3;              // k sub-offset within chunk (0,8,16,24)
  int hcol = wc * 64 + (l & 15);        // B-frag h (plus cf*16)

  f32x4 acc[4];
#pragma unroll
  for (int i = 0; i < 4; ++i) acc[i] = (f32x4){0.f, 0.f, 0.f, 0.f};

  char* PhB = (char*)Ph;
  char* PlB = (char*)Pl;

  for (int k0 = 0; k0 < SS; k0 += 64) {
    // ---- stage P tile (exp + split) into swizzled LDS ----
    if (mode == 0) {
      float4 u4 = *(const float4*)(Ub + (size_t)(r0 + srow) * SS + k0 + sc4);
      ushort4 h4, l4;
      ushort_t hh, ll;
      bsplit(__expf(u4.x - rm), hh, ll); h4.x = hh; l4.x = ll;
      bsplit(__expf(u4.y - rm), hh, ll); h4.y = hh; l4.y = ll;
      bsplit(__expf(u4.z - rm), hh, ll); h4.z = hh; l4.z = ll;
      bsplit(__expf(u4.w - rm), hh, ll); h4.w = hh; l4.w = ll;
      unsigned off = ((unsigned)(srow * 128 + sc4 * 2)) ^ (((unsigned)(srow & 7)) << 4);
      *(ushort4*)(PhB + off) = h4;
      *(ushort4*)(PlB + off) = l4;
    } else {
      float4 u4 = *(const float4*)(Ub + (size_t)(k0 + srow) * SS + r0 + sc4);
      float e[4] = {__expf(u4.x - cm4.x), __expf(u4.y - cm4.y),
                    __expf(u4.z - cm4.z), __expf(u4.w - cm4.w)};
#pragma unroll
      for (int j = 0; j < 4; ++j) {
        ushort_t hh, ll;
        bsplit(e[j], hh, ll);
        int rr = sc4 + j;
        unsigned off = ((unsigned)(rr * 128 + srow * 2)) ^ (((unsigned)(rr & 7)) << 4);
        *(ushort_t*)(PhB + off) = hh;
        *(ushort_t*)(PlB + off) = ll;
      }
    }
    __syncthreads();
    // ---- compute: 2 K-chunks of 32 ----
#pragma unroll
    for (int kc = 0; kc < 64; kc += 32) {
      int ak = kc + lk8;
      unsigned aoff = ((unsigned)(arow * 128 + ak * 2)) ^ arow_sw;
      bf16x8 ah = *(const bf16x8*)(PhB + aoff);
      bf16x8 al = *(const bf16x8*)(PlB + aoff);
      size_t kg = (size_t)(k0 + ak);
#pragma unroll
      for (int cf = 0; cf < 4; ++cf) {
        size_t bidx = ((size_t)b * HH + hcol + cf * 16) * SS + kg;
        bf16x8 bh = *(const bf16x8*)(Bh + bidx);
        bf16x8 bl = *(const bf16x8*)(Bl + bidx);
        acc[cf] = __builtin_amdgcn_mfma_f32_16x16x32_bf16(ah, bh, acc[cf], 0, 0, 0);
        acc[cf] = __builtin_amdgcn_mfma_f32_16x16x32_bf16(ah, bl, acc[cf], 0, 0, 0);
        acc[cf] = __builtin_amdgcn_mfma_f32_16x16x32_bf16(al, bh, acc[cf], 0, 0, 0);
      }
    }
    __syncthreads();
  }

  // ---- epilogue ----
  int crow = wr * 16 + ((l >> 4) << 2);  // + j
  if (LEVEL == 1) {
    const float* inv = mode == 0 ? rowinv : colinv;
    float* Out = mode == 0 ? A1w : B1w;
#pragma unroll
    for (int j = 0; j < 4; ++j) {
      int rr = r0 + crow + j;
      float sc = inv[bS + rr];
#pragma unroll
      for (int cf = 0; cf < 4; ++cf) {
        int h = hcol + cf * 16;
        Out[(bS + rr) * HH + h] = acc[cf][j] * sc;
      }
    }
  } else {
    if (mode == 0) {
      float* Gqp = out + GSEG;  // rows are p
#pragma unroll
      for (int j = 0; j < 4; ++j) {
        int rr = r0 + crow + j;
        float sc = rowinv[bS + rr];
#pragma unroll
        for (int cf = 0; cf < 4; ++cf) {
          int h = hcol + cf * 16;
          size_t eidx = (bS + rr) * HH + h;
          float a2 = acc[cf][j] * sc;
          float ep = Ep[eidx];
          float a1 = A1w[eidx];
          float* g = Gqp + (bS + rr) * (size_t)(5 * HH) + h;
          g[0 * HH] = ep;
          g[1 * HH] = a1;
          g[2 * HH] = a2;
          g[3 * HH] = ep * a1;
          g[4 * HH] = ep * a2;
        }
      }
    } else {
#pragma unroll
      for (int j = 0; j < 4; ++j) {
        int rr = r0 + crow + j;
        float sc = colinv[bS + rr];
#pragma unroll
        for (int cf = 0; cf < 4; ++cf) {
          int h = hcol + cf * 16;
          size_t eidx = (bS + rr) * HH + h;
          float b2 = acc[cf][j] * sc;
          float eq = Eq[eidx];
          float b1 = B1w[eidx];
          float* g = out + (bS + rr) * (size_t)(5 * HH) + h;
          g[0 * HH] = eq;
          g[1 * HH] = b1;
          g[2 * HH] = b2;
          g[3 * HH] = eq * b1;
          g[4 * HH] = eq * b2;
        }
      }
    }
  }
}

// ------------------------------------------------------------------
extern "C" void kernel_launch(void* const* d_in, const int* in_sizes, int n_in,
                              void* d_out, int out_size, void* d_ws, size_t ws_size,
                              hipStream_t stream) {
  const float* Eq = (const float*)d_in[0];
  const float* Ep = (const float*)d_in[1];
  const float* m1 = (const float*)d_in[2];
  const float* m2 = (const float*)d_in[3];
  const float* W  = (const float*)d_in[4];
  float* out = (float*)d_out;

  // workspace layout (floats); ~96 MB total with aliasing
  float* ws     = (float*)d_ws;
  float* U      = ws;                              // B*S*S fp32 (64 MB)
  float* rowmax = U + (size_t)BB * SS * SS;
  float* rowinv = rowmax + BB * SS;
  float* colmax = rowinv + BB * SS;
  float* colinv = colmax + BB * SS;
  float* spv    = colinv + BB * SS;
  float* sqv    = spv + BB * SS;
  float* A1w    = sqv + BB * SS;                   // B*S*H fp32 (8 MB)
  float* B1w    = A1w + NT;                        // B*S*H fp32 (8 MB)
  ushort_t* EqTh = (ushort_t*)(B1w + NT);          // 4 x (B*H*S) bf16 (16 MB)
  ushort_t* EqTl = EqTh + NT;
  ushort_t* EpTh = EqTl + NT;
  ushort_t* EpTl = EpTh + NT;
  // pm/ps alias A1w/B1w region: dead before k_level<1> writes A1w/B1w
  float* pm     = A1w;                             // 16*B*S floats (0.5 MB)
  float* ps     = pm + 16 * BB * SS;
  // A1T/B1T alias EqT/EpT storage: EqT/EpT dead after k_level<1>
  ushort_t* A1Th = EqTh;
  ushort_t* A1Tl = EqTl;
  ushort_t* B1Th = EpTh;
  ushort_t* B1Tl = EpTl;

  dim3 tcg(SS / 64, HH / 64, BB);

  k_rowdots<<<2 * BB * SS / 4, 256, 0, stream>>>(Eq, Ep, W, sqv, spv);
  k_tc<<<tcg, 256, 0, stream>>>(Eq, EqTh, EqTl);
  k_tc<<<tcg, 256, 0, stream>>>(Ep, EpTh, EpTl);
  k_tri<<<dim3(SS / 64, SS / 64, BB), 256, 0, stream>>>(Eq, Ep, W, m1, m2, spv, sqv, U);
  k_rowstats<<<BB * SS, 256, 0, stream>>>(U, rowmax, rowinv);
  k_colpart<<<dim3(SS / 256, 16, BB), 256, 0, stream>>>(U, pm, ps);
  k_colcomb<<<BB * SS / 256, 256, 0, stream>>>(pm, ps, colmax, colinv);
  k_level<1><<<dim3(SS / 64, 2, BB), 1024, 0, stream>>>(
      U, EqTh, EqTl, EpTh, EpTl, rowmax, rowinv, colmax, colinv,
      Eq, Ep, A1w, B1w, out);
  k_tc<<<tcg, 256, 0, stream>>>(A1w, A1Th, A1Tl);
  k_tc<<<tcg, 256, 0, stream>>>(B1w, B1Th, B1Tl);
  k_level<2><<<dim3(SS / 64, 2, BB), 1024, 0, stream>>>(
      U, B1Th, B1Tl, A1Th, A1Tl, rowmax, rowinv, colmax, colinv,
      Eq, Ep, A1w, B1w, out);
}

// Round 6
// 425.895 us; speedup vs baseline: 1.8984x; 1.8768x over previous
//
#include <hip/hip_runtime.h>
#include <math.h>

// Problem constants (from reference): B=4, SQ=SP=2048, H=256
#define BB 4
#define SS 2048
#define HH 256
#define NEG_BIG -1e9f
#define GSEG ((size_t)BB * SS * 5 * HH)  // elements per output tensor
#define NT ((size_t)BB * SS * HH)        // elements per E-like tensor

typedef unsigned short ushort_t;
typedef __attribute__((ext_vector_type(8))) __bf16 bf16x8;
typedef __attribute__((ext_vector_type(8))) unsigned short ushort8;
typedef __attribute__((ext_vector_type(4))) float f32x4;

// split fp32 into bf16 hi + bf16 lo (RNE both)
__device__ __forceinline__ void bsplit(float x, ushort_t& hi, ushort_t& lo) {
  union { float f; unsigned u; } a; a.f = x;
  unsigned r = a.u + 0x7FFFu + ((a.u >> 16) & 1u);
  ushort_t h = (ushort_t)(r >> 16);
  union { unsigned u; float f; } hf; hf.u = ((unsigned)h) << 16;
  float l = x - hf.f;
  union { float f; unsigned u; } b; b.f = l;
  unsigned r2 = b.u + 0x7FFFu + ((b.u >> 16) & 1u);
  hi = h; lo = (ushort_t)(r2 >> 16);
}

// ------------------------------------------------------------------
// K0: sp[b,p] = dot(E_p[b,p,:], w_p);  sq[b,q] = dot(E_q[b,q,:], w_q)
// ------------------------------------------------------------------
__global__ __launch_bounds__(256) void k_rowdots(
    const float* __restrict__ Eq, const float* __restrict__ Ep,
    const float* __restrict__ W,
    float* __restrict__ sqv, float* __restrict__ spv) {
  int g = blockIdx.x * 256 + threadIdx.x;
  int wid = g >> 6;
  int lane = g & 63;
  const int total = BB * SS;
  int isp = wid >= total;
  int row = isp ? (wid - total) : wid;
  const float* Er = (isp ? Ep : Eq) + (size_t)row * HH;
  const float* w = W + (isp ? HH : 0);
  float4 e = ((const float4*)Er)[lane];
  float4 wv = ((const float4*)w)[lane];
  float acc = e.x * wv.x + e.y * wv.y + e.z * wv.z + e.w * wv.w;
#pragma unroll
  for (int off = 32; off > 0; off >>= 1) acc += __shfl_down(acc, off, 64);
  if (lane == 0) (isp ? spv : sqv)[row] = acc;
}

// ------------------------------------------------------------------
// K_tc: transpose-convert  src fp32 [b][r<SS][h<HH]  ->  dhi/dlo bf16 [b][h][r]
// ------------------------------------------------------------------
__global__ __launch_bounds__(256) void k_tc(
    const float* __restrict__ src, ushort_t* __restrict__ dhi, ushort_t* __restrict__ dlo) {
  __shared__ float tile[64][65];
  int b = blockIdx.z;
  int r0 = blockIdx.x << 6;
  int h0 = blockIdx.y << 6;
  int tid = threadIdx.x;
  int rl = tid >> 4, c4 = (tid & 15) << 2;
  size_t srcb = (size_t)b * SS * HH;
#pragma unroll
  for (int i = 0; i < 4; ++i) {
    float4 v = *(const float4*)(src + srcb + (size_t)(r0 + rl + 16 * i) * HH + h0 + c4);
    tile[rl + 16 * i][c4 + 0] = v.x;
    tile[rl + 16 * i][c4 + 1] = v.y;
    tile[rl + 16 * i][c4 + 2] = v.z;
    tile[rl + 16 * i][c4 + 3] = v.w;
  }
  __syncthreads();
  size_t dstb = (size_t)b * HH;
#pragma unroll
  for (int i = 0; i < 4; ++i) {
    int h = rl + 16 * i;
    ushort4 h4, l4;
    ushort_t hh, ll;
    bsplit(tile[c4 + 0][h], hh, ll); h4.x = hh; l4.x = ll;
    bsplit(tile[c4 + 1][h], hh, ll); h4.y = hh; l4.y = ll;
    bsplit(tile[c4 + 2][h], hh, ll); h4.z = hh; l4.z = ll;
    bsplit(tile[c4 + 3][h], hh, ll); h4.w = hh; l4.w = ll;
    size_t o = (dstb + h0 + h) * SS + r0 + c4;
    *(ushort4*)(dhi + o) = h4;
    *(ushort4*)(dlo + o) = l4;
  }
}

// ------------------------------------------------------------------
// K1: U[b,p,q] = dot(E_p[b,p,:]*w_m, E_q[b,q,:]) + sp + sq, masked (fp32)
// ------------------------------------------------------------------
__global__ __launch_bounds__(256) void k_tri(
    const float* __restrict__ Eq, const float* __restrict__ Ep,
    const float* __restrict__ W,
    const float* __restrict__ m1, const float* __restrict__ m2,
    const float* __restrict__ spv, const float* __restrict__ sqv,
    float* __restrict__ U) {
  alignas(16) __shared__ float As[32][68];
  alignas(16) __shared__ float Bs[32][68];
  int b = blockIdx.z;
  int q0 = blockIdx.x << 6;
  int p0 = blockIdx.y << 6;
  int tid = threadIdx.x;
  int tx = tid & 15, ty = tid >> 4;
  size_t bS = (size_t)b * SS;
  const float* EpB = Ep + bS * HH;
  const float* EqB = Eq + bS * HH;
  const float* wm = W + 2 * HH;
  float acc[4][4] = {};
  for (int k0 = 0; k0 < HH; k0 += 32) {
#pragma unroll
    for (int i = 0; i < 2; ++i) {
      int idx = tid + i * 256;
      int r = idx >> 3;
      int c4 = (idx & 7) << 2;
      float4 w4 = *(const float4*)(wm + k0 + c4);
      float4 a4 = *(const float4*)(EpB + (size_t)(p0 + r) * HH + k0 + c4);
      float4 b4 = *(const float4*)(EqB + (size_t)(q0 + r) * HH + k0 + c4);
      As[c4 + 0][r] = a4.x * w4.x;
      As[c4 + 1][r] = a4.y * w4.y;
      As[c4 + 2][r] = a4.z * w4.z;
      As[c4 + 3][r] = a4.w * w4.w;
      Bs[c4 + 0][r] = b4.x;
      Bs[c4 + 1][r] = b4.y;
      Bs[c4 + 2][r] = b4.z;
      Bs[c4 + 3][r] = b4.w;
    }
    __syncthreads();
#pragma unroll
    for (int k = 0; k < 32; ++k) {
      float4 a4 = *(const float4*)&As[k][ty << 2];
      float4 b4 = *(const float4*)&Bs[k][tx << 2];
      acc[0][0] += a4.x * b4.x; acc[0][1] += a4.x * b4.y; acc[0][2] += a4.x * b4.z; acc[0][3] += a4.x * b4.w;
      acc[1][0] += a4.y * b4.x; acc[1][1] += a4.y * b4.y; acc[1][2] += a4.y * b4.z; acc[1][3] += a4.y * b4.w;
      acc[2][0] += a4.z * b4.x; acc[2][1] += a4.z * b4.y; acc[2][2] += a4.z * b4.z; acc[2][3] += a4.z * b4.w;
      acc[3][0] += a4.w * b4.x; acc[3][1] += a4.w * b4.y; acc[3][2] += a4.w * b4.z; acc[3][3] += a4.w * b4.w;
    }
    __syncthreads();
  }
  int prow = p0 + (ty << 2);
  int qcol = q0 + (tx << 2);
  float spr[4], mpr[4], sqc[4], mqc[4];
#pragma unroll
  for (int i = 0; i < 4; ++i) { spr[i] = spv[bS + prow + i]; mpr[i] = m1[bS + prow + i]; }
#pragma unroll
  for (int j = 0; j < 4; ++j) { sqc[j] = sqv[bS + qcol + j]; mqc[j] = m2[bS + qcol + j]; }
#pragma unroll
  for (int i = 0; i < 4; ++i) {
    float4 o;
    o.x = (mpr[i] * mqc[0] < 0.5f) ? NEG_BIG : (acc[i][0] + spr[i] + sqc[0]);
    o.y = (mpr[i] * mqc[1] < 0.5f) ? NEG_BIG : (acc[i][1] + spr[i] + sqc[1]);
    o.z = (mpr[i] * mqc[2] < 0.5f) ? NEG_BIG : (acc[i][2] + spr[i] + sqc[2]);
    o.w = (mpr[i] * mqc[3] < 0.5f) ? NEG_BIG : (acc[i][3] + spr[i] + sqc[3]);
    *(float4*)(U + (bS + prow + i) * SS + qcol) = o;
  }
}

// ------------------------------------------------------------------
// K2: row softmax stats (axis=2, over q)
// ------------------------------------------------------------------
__global__ __launch_bounds__(256) void k_rowstats(
    const float* __restrict__ U, float* __restrict__ rowmax, float* __restrict__ rowinv) {
  __shared__ float redm[4];
  __shared__ float reds[4];
  int row = blockIdx.x;
  int tid = threadIdx.x;
  const float* u = U + (size_t)row * SS;
  float4 v1 = ((const float4*)u)[tid];
  float4 v2 = ((const float4*)u)[tid + 256];
  float m = fmaxf(fmaxf(fmaxf(v1.x, v1.y), fmaxf(v1.z, v1.w)),
                  fmaxf(fmaxf(v2.x, v2.y), fmaxf(v2.z, v2.w)));
#pragma unroll
  for (int off = 32; off > 0; off >>= 1) m = fmaxf(m, __shfl_down(m, off, 64));
  if ((tid & 63) == 0) redm[tid >> 6] = m;
  __syncthreads();
  m = fmaxf(fmaxf(redm[0], redm[1]), fmaxf(redm[2], redm[3]));
  float s = __expf(v1.x - m) + __expf(v1.y - m) + __expf(v1.z - m) + __expf(v1.w - m)
          + __expf(v2.x - m) + __expf(v2.y - m) + __expf(v2.z - m) + __expf(v2.w - m);
#pragma unroll
  for (int off = 32; off > 0; off >>= 1) s += __shfl_down(s, off, 64);
  if ((tid & 63) == 0) reds[tid >> 6] = s;
  __syncthreads();
  if (tid == 0) {
    float st = reds[0] + reds[1] + reds[2] + reds[3];
    rowmax[row] = m;
    rowinv[row] = 1.0f / st;
  }
}

// ------------------------------------------------------------------
// K3a/K3b: column softmax stats (axis=1, over p)
// ------------------------------------------------------------------
__global__ __launch_bounds__(256) void k_colpart(
    const float* __restrict__ U, float* __restrict__ pm, float* __restrict__ ps) {
  int q = blockIdx.x * 256 + threadIdx.x;
  int pc = blockIdx.y;
  int b = blockIdx.z;
  const float* u = U + ((size_t)b * SS + pc * 128) * SS + q;
  float m = -INFINITY, s = 0.f;
  for (int p = 0; p < 128; ++p) {
    float x = u[(size_t)p * SS];
    float nm = fmaxf(m, x);
    s = s * __expf(m - nm) + __expf(x - nm);
    m = nm;
  }
  int o = (pc * BB + b) * SS + q;
  pm[o] = m;
  ps[o] = s;
}

__global__ __launch_bounds__(256) void k_colcomb(
    const float* __restrict__ pm, const float* __restrict__ ps,
    float* __restrict__ colmax, float* __restrict__ colinv) {
  int i = blockIdx.x * 256 + threadIdx.x;
  float m = -INFINITY;
#pragma unroll
  for (int pc = 0; pc < 16; ++pc) m = fmaxf(m, pm[(size_t)pc * BB * SS + i]);
  float s = 0.f;
#pragma unroll
  for (int pc = 0; pc < 16; ++pc)
    s += ps[(size_t)pc * BB * SS + i] * __expf(pm[(size_t)pc * BB * SS + i] - m);
  colmax[i] = m;
  colinv[i] = 1.0f / s;
}

// ------------------------------------------------------------------
// MFMA level kernels: Out[r,h] = sum_k exp(U - max) * E[k,h]
// split-bf16 3-MFMA (PhEh + PhEl + PlEh) = fp32-level accuracy.
// Block: 512 thr = 8 waves (2 row-groups x 4 col-groups).
// Tile: 32 rows x 256 h, BK=64. B^T chunk staged in LDS (shared by waves).
// All LDS tiles XOR-swizzled: byte ^= (row&7)<<4 (G4 fix for stride-128B).
// mode 0: rows=p, k=q, P = exp(U[p,q]-rowmax[p])
// mode 1: rows=q, k=p, P = exp(U[p,q]-colmax[q])
// ------------------------------------------------------------------
template <int LEVEL>
__global__ __launch_bounds__(512, 4) void k_level(
    const float* __restrict__ U,
    const ushort_t* __restrict__ B0h, const ushort_t* __restrict__ B0l,
    const ushort_t* __restrict__ B1h, const ushort_t* __restrict__ B1l,
    const float* __restrict__ rowmax, const float* __restrict__ rowinv,
    const float* __restrict__ colmax, const float* __restrict__ colinv,
    const float* __restrict__ Eq, const float* __restrict__ Ep,
    float* __restrict__ A1w, float* __restrict__ B1w,
    float* __restrict__ out) {
  __shared__ ushort_t Ph[32 * 64];    // 4 KB
  __shared__ ushort_t Pl[32 * 64];    // 4 KB
  __shared__ ushort_t Bsh[256 * 64];  // 32 KB
  __shared__ ushort_t Bsl[256 * 64];  // 32 KB
  int b = blockIdx.z;
  int mode = blockIdx.y;
  int r0 = blockIdx.x << 5;
  int tid = threadIdx.x;
  size_t bS = (size_t)b * SS;
  const float* Ub = U + bS * SS;
  const ushort_t* Bh = (mode == 0 ? B0h : B1h) + (size_t)b * HH * SS;
  const ushort_t* Bl = (mode == 0 ? B0l : B1l) + (size_t)b * HH * SS;

  // P staging indices
  int srow0 = tid >> 4;           // mode0: p row 0..31
  int sc40 = (tid & 15) << 2;     // mode0: q (k) 0..60
  int srow1 = tid >> 3;           // mode1: p (k) 0..63
  int sc41 = (tid & 7) << 2;      // mode1: q col 0..28
  float rm = 0.f;
  float4 cm4;
  if (mode == 0) rm = rowmax[bS + r0 + srow0];
  else cm4 = *(const float4*)(colmax + bS + r0 + sc41);

  // wave / fragment indices
  int w = tid >> 6, l = tid & 63;
  int wr = w >> 2, wc = w & 3;          // 2x4 wave grid
  int arow = wr * 16 + (l & 15);        // A-frag row 0..31
  unsigned asw = ((unsigned)(arow & 7)) << 4;
  int lk8 = (l >> 4) << 3;              // k sub-offset (0,8,16,24)
  int hcol = wc * 64 + (l & 15);        // B-frag h (plus cf*16)

  f32x4 acc[4];
#pragma unroll
  for (int i = 0; i < 4; ++i) acc[i] = (f32x4){0.f, 0.f, 0.f, 0.f};

  char* PhB = (char*)Ph;
  char* PlB = (char*)Pl;
  char* BhB = (char*)Bsh;
  char* BlB = (char*)Bsl;

  for (int k0 = 0; k0 < SS; k0 += 64) {
    // ---- stage B^T chunk [256 h][64 k] into swizzled LDS ----
#pragma unroll
    for (int i = 0; i < 4; ++i) {
      int idx = tid + i * 512;
      int h = idx >> 3;
      int k8 = (idx & 7) << 3;
      unsigned off = ((unsigned)(h * 128 + k8 * 2)) ^ (((unsigned)(h & 7)) << 4);
      *(ushort8*)(BhB + off) = *(const ushort8*)(Bh + (size_t)h * SS + k0 + k8);
      *(ushort8*)(BlB + off) = *(const ushort8*)(Bl + (size_t)h * SS + k0 + k8);
    }
    // ---- stage P tile (exp + split) into swizzled LDS ----
    if (mode == 0) {
      float4 u4 = *(const float4*)(Ub + (size_t)(r0 + srow0) * SS + k0 + sc40);
      ushort4 h4, l4;
      ushort_t hh, ll;
      bsplit(__expf(u4.x - rm), hh, ll); h4.x = hh; l4.x = ll;
      bsplit(__expf(u4.y - rm), hh, ll); h4.y = hh; l4.y = ll;
      bsplit(__expf(u4.z - rm), hh, ll); h4.z = hh; l4.z = ll;
      bsplit(__expf(u4.w - rm), hh, ll); h4.w = hh; l4.w = ll;
      unsigned off = ((unsigned)(srow0 * 128 + sc40 * 2)) ^ (((unsigned)(srow0 & 7)) << 4);
      *(ushort4*)(PhB + off) = h4;
      *(ushort4*)(PlB + off) = l4;
    } else {
      float4 u4 = *(const float4*)(Ub + (size_t)(k0 + srow1) * SS + r0 + sc41);
      float e[4] = {__expf(u4.x - cm4.x), __expf(u4.y - cm4.y),
                    __expf(u4.z - cm4.z), __expf(u4.w - cm4.w)};
#pragma unroll
      for (int j = 0; j < 4; ++j) {
        ushort_t hh, ll;
        bsplit(e[j], hh, ll);
        int rr = sc41 + j;
        unsigned off = ((unsigned)(rr * 128 + srow1 * 2)) ^ (((unsigned)(rr & 7)) << 4);
        *(ushort_t*)(PhB + off) = hh;
        *(ushort_t*)(PlB + off) = ll;
      }
    }
    __syncthreads();
    // ---- compute: 2 K-chunks of 32 ----
#pragma unroll
    for (int kc = 0; kc < 64; kc += 32) {
      int ak = kc + lk8;
      unsigned aoff = ((unsigned)(arow * 128 + ak * 2)) ^ asw;
      bf16x8 ah = *(const bf16x8*)(PhB + aoff);
      bf16x8 al = *(const bf16x8*)(PlB + aoff);
#pragma unroll
      for (int cf = 0; cf < 4; ++cf) {
        int h = hcol + cf * 16;
        unsigned boff = ((unsigned)(h * 128 + ak * 2)) ^ (((unsigned)(h & 7)) << 4);
        bf16x8 bh = *(const bf16x8*)(BhB + boff);
        bf16x8 bl = *(const bf16x8*)(BlB + boff);
        acc[cf] = __builtin_amdgcn_mfma_f32_16x16x32_bf16(ah, bh, acc[cf], 0, 0, 0);
        acc[cf] = __builtin_amdgcn_mfma_f32_16x16x32_bf16(ah, bl, acc[cf], 0, 0, 0);
        acc[cf] = __builtin_amdgcn_mfma_f32_16x16x32_bf16(al, bh, acc[cf], 0, 0, 0);
      }
    }
    __syncthreads();
  }

  // ---- epilogue ----
  int crow = wr * 16 + ((l >> 4) << 2);  // + j, 0..31
  if (LEVEL == 1) {
    const float* inv = mode == 0 ? rowinv : colinv;
    float* Out = mode == 0 ? A1w : B1w;
#pragma unroll
    for (int j = 0; j < 4; ++j) {
      int rr = r0 + crow + j;
      float sc = inv[bS + rr];
#pragma unroll
      for (int cf = 0; cf < 4; ++cf) {
        int h = hcol + cf * 16;
        Out[(bS + rr) * HH + h] = acc[cf][j] * sc;
      }
    }
  } else {
    if (mode == 0) {
      float* Gqp = out + GSEG;  // rows are p
#pragma unroll
      for (int j = 0; j < 4; ++j) {
        int rr = r0 + crow + j;
        float sc = rowinv[bS + rr];
#pragma unroll
        for (int cf = 0; cf < 4; ++cf) {
          int h = hcol + cf * 16;
          size_t eidx = (bS + rr) * HH + h;
          float a2 = acc[cf][j] * sc;
          float ep = Ep[eidx];
          float a1 = A1w[eidx];
          float* g = Gqp + (bS + rr) * (size_t)(5 * HH) + h;
          g[0 * HH] = ep;
          g[1 * HH] = a1;
          g[2 * HH] = a2;
          g[3 * HH] = ep * a1;
          g[4 * HH] = ep * a2;
        }
      }
    } else {
#pragma unroll
      for (int j = 0; j < 4; ++j) {
        int rr = r0 + crow + j;
        float sc = colinv[bS + rr];
#pragma unroll
        for (int cf = 0; cf < 4; ++cf) {
          int h = hcol + cf * 16;
          size_t eidx = (bS + rr) * HH + h;
          float b2 = acc[cf][j] * sc;
          float eq = Eq[eidx];
          float b1 = B1w[eidx];
          float* g = out + (bS + rr) * (size_t)(5 * HH) + h;
          g[0 * HH] = eq;
          g[1 * HH] = b1;
          g[2 * HH] = b2;
          g[3 * HH] = eq * b1;
          g[4 * HH] = eq * b2;
        }
      }
    }
  }
}

// ------------------------------------------------------------------
extern "C" void kernel_launch(void* const* d_in, const int* in_sizes, int n_in,
                              void* d_out, int out_size, void* d_ws, size_t ws_size,
                              hipStream_t stream) {
  const float* Eq = (const float*)d_in[0];
  const float* Ep = (const float*)d_in[1];
  const float* m1 = (const float*)d_in[2];
  const float* m2 = (const float*)d_in[3];
  const float* W  = (const float*)d_in[4];
  float* out = (float*)d_out;

  // workspace layout (floats); ~96 MB total with aliasing
  float* ws     = (float*)d_ws;
  float* U      = ws;                              // B*S*S fp32 (64 MB)
  float* rowmax = U + (size_t)BB * SS * SS;
  float* rowinv = rowmax + BB * SS;
  float* colmax = rowinv + BB * SS;
  float* colinv = colmax + BB * SS;
  float* spv    = colinv + BB * SS;
  float* sqv    = spv + BB * SS;
  float* A1w    = sqv + BB * SS;                   // B*S*H fp32 (8 MB)
  float* B1w    = A1w + NT;                        // B*S*H fp32 (8 MB)
  ushort_t* EqTh = (ushort_t*)(B1w + NT);          // 4 x (B*H*S) bf16 (16 MB)
  ushort_t* EqTl = EqTh + NT;
  ushort_t* EpTh = EqTl + NT;
  ushort_t* EpTl = EpTh + NT;
  // pm/ps alias A1w/B1w region: dead before k_level<1> writes A1w/B1w
  float* pm     = A1w;                             // 16*B*S floats (0.5 MB)
  float* ps     = pm + 16 * BB * SS;
  // A1T/B1T alias EqT/EpT storage: EqT/EpT dead after k_level<1>
  ushort_t* A1Th = EqTh;
  ushort_t* A1Tl = EqTl;
  ushort_t* B1Th = EpTh;
  ushort_t* B1Tl = EpTl;

  dim3 tcg(SS / 64, HH / 64, BB);

  k_rowdots<<<2 * BB * SS / 4, 256, 0, stream>>>(Eq, Ep, W, sqv, spv);
  k_tc<<<tcg, 256, 0, stream>>>(Eq, EqTh, EqTl);
  k_tc<<<tcg, 256, 0, stream>>>(Ep, EpTh, EpTl);
  k_tri<<<dim3(SS / 64, SS / 64, BB), 256, 0, stream>>>(Eq, Ep, W, m1, m2, spv, sqv, U);
  k_rowstats<<<BB * SS, 256, 0, stream>>>(U, rowmax, rowinv);
  k_colpart<<<dim3(SS / 256, 16, BB), 256, 0, stream>>>(U, pm, ps);
  k_colcomb<<<BB * SS / 256, 256, 0, stream>>>(pm, ps, colmax, colinv);
  k_level<1><<<dim3(SS / 32, 2, BB), 512, 0, stream>>>(
      U, EqTh, EqTl, EpTh, EpTl, rowmax, rowinv, colmax, colinv,
      Eq, Ep, A1w, B1w, out);
  k_tc<<<tcg, 256, 0, stream>>>(A1w, A1Th, A1Tl);
  k_tc<<<tcg, 256, 0, stream>>>(B1w, B1Th, B1Tl);
  k_level<2><<<dim3(SS / 32, 2, BB), 512, 0, stream>>>(
      U, B1Th, B1Tl, A1Th, A1Tl, rowmax, rowinv, colmax, colinv,
      Eq, Ep, A1w, B1w, out);
}

// Round 9
// 358.703 us; speedup vs baseline: 2.2540x; 1.1873x over previous
//
#include <hip/hip_runtime.h>
#include <math.h>

// Problem constants (from reference): B=4, SQ=SP=2048, H=256
#define BB 4
#define SS 2048
#define HH 256
#define NEG_BIG -1e9f
#define GSEG ((size_t)BB * SS * 5 * HH)  // elements per output tensor
#define NT ((size_t)BB * SS * HH)        // elements per E-like tensor

typedef unsigned short ushort_t;
typedef __attribute__((ext_vector_type(8))) __bf16 bf16x8;
typedef __attribute__((ext_vector_type(8))) unsigned short ushort8;
typedef __attribute__((ext_vector_type(4))) float f32x4;

// split fp32 into bf16 hi + bf16 lo (RNE both)
__device__ __forceinline__ void bsplit(float x, ushort_t& hi, ushort_t& lo) {
  union { float f; unsigned u; } a; a.f = x;
  unsigned r = a.u + 0x7FFFu + ((a.u >> 16) & 1u);
  ushort_t h = (ushort_t)(r >> 16);
  union { unsigned u; float f; } hf; hf.u = ((unsigned)h) << 16;
  float l = x - hf.f;
  union { float f; unsigned u; } b; b.f = l;
  unsigned r2 = b.u + 0x7FFFu + ((b.u >> 16) & 1u);
  hi = h; lo = (ushort_t)(r2 >> 16);
}

// ------------------------------------------------------------------
// K0: sp[b,p] = dot(E_p[b,p,:], w_p);  sq[b,q] = dot(E_q[b,q,:], w_q)
// ------------------------------------------------------------------
__global__ __launch_bounds__(256) void k_rowdots(
    const float* __restrict__ Eq, const float* __restrict__ Ep,
    const float* __restrict__ W,
    float* __restrict__ sqv, float* __restrict__ spv) {
  int g = blockIdx.x * 256 + threadIdx.x;
  int wid = g >> 6;
  int lane = g & 63;
  const int total = BB * SS;
  int isp = wid >= total;
  int row = isp ? (wid - total) : wid;
  const float* Er = (isp ? Ep : Eq) + (size_t)row * HH;
  const float* w = W + (isp ? HH : 0);
  float4 e = ((const float4*)Er)[lane];
  float4 wv = ((const float4*)w)[lane];
  float acc = e.x * wv.x + e.y * wv.y + e.z * wv.z + e.w * wv.w;
#pragma unroll
  for (int off = 32; off > 0; off >>= 1) acc += __shfl_down(acc, off, 64);
  if (lane == 0) (isp ? spv : sqv)[row] = acc;
}

// ------------------------------------------------------------------
// K_rc: row-major split convert. src fp32 [b][r][h] (* optional wm[h])
//       -> dh/dl bf16 [b][r][h]. 8 elements/thread.
// ------------------------------------------------------------------
__global__ __launch_bounds__(256) void k_rc(
    const float* __restrict__ src, const float* __restrict__ wm,
    ushort_t* __restrict__ dh, ushort_t* __restrict__ dl) {
  size_t i = ((size_t)blockIdx.x * 256 + threadIdx.x) * 8;
  float4 v0 = *(const float4*)(src + i);
  float4 v1 = *(const float4*)(src + i + 4);
  if (wm) {
    int h = (int)(i & (HH - 1));
    float4 w0 = *(const float4*)(wm + h);
    float4 w1 = *(const float4*)(wm + h + 4);
    v0.x *= w0.x; v0.y *= w0.y; v0.z *= w0.z; v0.w *= w0.w;
    v1.x *= w1.x; v1.y *= w1.y; v1.z *= w1.z; v1.w *= w1.w;
  }
  ushort8 h8, l8;
  ushort_t hh, ll;
  bsplit(v0.x, hh, ll); h8[0] = hh; l8[0] = ll;
  bsplit(v0.y, hh, ll); h8[1] = hh; l8[1] = ll;
  bsplit(v0.z, hh, ll); h8[2] = hh; l8[2] = ll;
  bsplit(v0.w, hh, ll); h8[3] = hh; l8[3] = ll;
  bsplit(v1.x, hh, ll); h8[4] = hh; l8[4] = ll;
  bsplit(v1.y, hh, ll); h8[5] = hh; l8[5] = ll;
  bsplit(v1.z, hh, ll); h8[6] = hh; l8[6] = ll;
  bsplit(v1.w, hh, ll); h8[7] = hh; l8[7] = ll;
  *(ushort8*)(dh + i) = h8;
  *(ushort8*)(dl + i) = l8;
}

// ------------------------------------------------------------------
// K_tc: transpose-convert  src fp32 [b][r<SS][h<HH]  ->  dhi/dlo bf16 [b][h][r]
// ------------------------------------------------------------------
__global__ __launch_bounds__(256) void k_tc(
    const float* __restrict__ src, ushort_t* __restrict__ dhi, ushort_t* __restrict__ dlo) {
  __shared__ float tile[64][65];
  int b = blockIdx.z;
  int r0 = blockIdx.x << 6;
  int h0 = blockIdx.y << 6;
  int tid = threadIdx.x;
  int rl = tid >> 4, c4 = (tid & 15) << 2;
  size_t srcb = (size_t)b * SS * HH;
#pragma unroll
  for (int i = 0; i < 4; ++i) {
    float4 v = *(const float4*)(src + srcb + (size_t)(r0 + rl + 16 * i) * HH + h0 + c4);
    tile[rl + 16 * i][c4 + 0] = v.x;
    tile[rl + 16 * i][c4 + 1] = v.y;
    tile[rl + 16 * i][c4 + 2] = v.z;
    tile[rl + 16 * i][c4 + 3] = v.w;
  }
  __syncthreads();
  size_t dstb = (size_t)b * HH;
#pragma unroll
  for (int i = 0; i < 4; ++i) {
    int h = rl + 16 * i;
    ushort4 h4, l4;
    ushort_t hh, ll;
    bsplit(tile[c4 + 0][h], hh, ll); h4.x = hh; l4.x = ll;
    bsplit(tile[c4 + 1][h], hh, ll); h4.y = hh; l4.y = ll;
    bsplit(tile[c4 + 2][h], hh, ll); h4.z = hh; l4.z = ll;
    bsplit(tile[c4 + 3][h], hh, ll); h4.w = hh; l4.w = ll;
    size_t o = (dstb + h0 + h) * SS + r0 + c4;
    *(ushort4*)(dhi + o) = h4;
    *(ushort4*)(dlo + o) = l4;
  }
}

// ------------------------------------------------------------------
// K1 (MFMA): U[b,p,q] = sum_h (Ep*wm)[p,h]*Eq[q,h] + sp[p] + sq[q], masked.
// Inputs pre-split row-major bf16 hi/lo (k_rc). Block: 512 thr = 8 waves
// (2x4). Tile 32 p x 256 q, BK=64, K=256. Same swizzled-LDS fragment
// plumbing as k_level (HW-validated round 3/6).
// ------------------------------------------------------------------
__global__ __launch_bounds__(512, 4) void k_trim(
    const ushort_t* __restrict__ Ah_g, const ushort_t* __restrict__ Al_g,  // (Ep*wm) split
    const ushort_t* __restrict__ Bh_g, const ushort_t* __restrict__ Bl_g,  // Eq split
    const float* __restrict__ m1, const float* __restrict__ m2,
    const float* __restrict__ spv, const float* __restrict__ sqv,
    float* __restrict__ U) {
  __shared__ ushort_t Ash[32 * 64];   // 4 KB
  __shared__ ushort_t Asl[32 * 64];   // 4 KB
  __shared__ ushort_t Bsh[256 * 64];  // 32 KB
  __shared__ ushort_t Bsl[256 * 64];  // 32 KB
  int b = blockIdx.z;
  int q0 = blockIdx.x << 8;  // 256-wide q tile
  int p0 = blockIdx.y << 5;  // 32-wide p tile
  int tid = threadIdx.x;
  size_t bS = (size_t)b * SS;

  int w = tid >> 6, l = tid & 63;
  int wr = w >> 2, wc = w & 3;          // 2x4 wave grid
  int arow = wr * 16 + (l & 15);        // A-frag p row 0..31
  unsigned asw = ((unsigned)(arow & 7)) << 4;
  int lk8 = (l >> 4) << 3;              // k sub-offset (0,8,16,24)
  int qcl = wc * 64 + (l & 15);         // B-frag q col base (plus cf*16)

  f32x4 acc[4];
#pragma unroll
  for (int i = 0; i < 4; ++i) acc[i] = (f32x4){0.f, 0.f, 0.f, 0.f};

  char* AshB = (char*)Ash;
  char* AslB = (char*)Asl;
  char* BshB = (char*)Bsh;
  char* BslB = (char*)Bsl;

  for (int k0 = 0; k0 < HH; k0 += 64) {
    // stage A: 32 p-rows x 64 h (256 threads, ushort8 each)
    if (tid < 256) {
      int row = tid >> 3;
      int k8 = (tid & 7) << 3;
      unsigned off = ((unsigned)(row * 128 + k8 * 2)) ^ (((unsigned)(row & 7)) << 4);
      size_t g = (bS + p0 + row) * HH + k0 + k8;
      *(ushort8*)(AshB + off) = *(const ushort8*)(Ah_g + g);
      *(ushort8*)(AslB + off) = *(const ushort8*)(Al_g + g);
    }
    // stage B: 256 q-rows x 64 h
#pragma unroll
    for (int i = 0; i < 4; ++i) {
      int idx = tid + i * 512;
      int row = idx >> 3;
      int k8 = (idx & 7) << 3;
      unsigned off = ((unsigned)(row * 128 + k8 * 2)) ^ (((unsigned)(row & 7)) << 4);
      size_t g = (bS + q0 + row) * HH + k0 + k8;
      *(ushort8*)(BshB + off) = *(const ushort8*)(Bh_g + g);
      *(ushort8*)(BslB + off) = *(const ushort8*)(Bl_g + g);
    }
    __syncthreads();
#pragma unroll
    for (int kc = 0; kc < 64; kc += 32) {
      int ak = kc + lk8;
      unsigned aoff = ((unsigned)(arow * 128 + ak * 2)) ^ asw;
      bf16x8 ah = *(const bf16x8*)(AshB + aoff);
      bf16x8 al = *(const bf16x8*)(AslB + aoff);
#pragma unroll
      for (int cf = 0; cf < 4; ++cf) {
        int r = qcl + cf * 16;
        unsigned boff = ((unsigned)(r * 128 + ak * 2)) ^ (((unsigned)(r & 7)) << 4);
        bf16x8 bh = *(const bf16x8*)(BshB + boff);
        bf16x8 bl = *(const bf16x8*)(BslB + boff);
        acc[cf] = __builtin_amdgcn_mfma_f32_16x16x32_bf16(ah, bh, acc[cf], 0, 0, 0);
        acc[cf] = __builtin_amdgcn_mfma_f32_16x16x32_bf16(ah, bl, acc[cf], 0, 0, 0);
        acc[cf] = __builtin_amdgcn_mfma_f32_16x16x32_bf16(al, bh, acc[cf], 0, 0, 0);
      }
    }
    __syncthreads();
  }

  // epilogue: + sp + sq, mask, store U
  int crow = wr * 16 + ((l >> 4) << 2);  // + j
  float spr[4], mpr[4];
#pragma unroll
  for (int j = 0; j < 4; ++j) {
    spr[j] = spv[bS + p0 + crow + j];
    mpr[j] = m1[bS + p0 + crow + j];
  }
#pragma unroll
  for (int cf = 0; cf < 4; ++cf) {
    int q = q0 + qcl + cf * 16;
    float sqc = sqv[bS + q];
    float mqc = m2[bS + q];
#pragma unroll
    for (int j = 0; j < 4; ++j) {
      int p = p0 + crow + j;
      float v = acc[cf][j] + spr[j] + sqc;
      if (mpr[j] * mqc < 0.5f) v = NEG_BIG;
      U[(bS + p) * SS + q] = v;
    }
  }
}

// ------------------------------------------------------------------
// K2: row softmax stats (axis=2, over q)
// ------------------------------------------------------------------
__global__ __launch_bounds__(256) void k_rowstats(
    const float* __restrict__ U, float* __restrict__ rowmax, float* __restrict__ rowinv) {
  __shared__ float redm[4];
  __shared__ float reds[4];
  int row = blockIdx.x;
  int tid = threadIdx.x;
  const float* u = U + (size_t)row * SS;
  float4 v1 = ((const float4*)u)[tid];
  float4 v2 = ((const float4*)u)[tid + 256];
  float m = fmaxf(fmaxf(fmaxf(v1.x, v1.y), fmaxf(v1.z, v1.w)),
                  fmaxf(fmaxf(v2.x, v2.y), fmaxf(v2.z, v2.w)));
#pragma unroll
  for (int off = 32; off > 0; off >>= 1) m = fmaxf(m, __shfl_down(m, off, 64));
  if ((tid & 63) == 0) redm[tid >> 6] = m;
  __syncthreads();
  m = fmaxf(fmaxf(redm[0], redm[1]), fmaxf(redm[2], redm[3]));
  float s = __expf(v1.x - m) + __expf(v1.y - m) + __expf(v1.z - m) + __expf(v1.w - m)
          + __expf(v2.x - m) + __expf(v2.y - m) + __expf(v2.z - m) + __expf(v2.w - m);
#pragma unroll
  for (int off = 32; off > 0; off >>= 1) s += __shfl_down(s, off, 64);
  if ((tid & 63) == 0) reds[tid >> 6] = s;
  __syncthreads();
  if (tid == 0) {
    float st = reds[0] + reds[1] + reds[2] + reds[3];
    rowmax[row] = m;
    rowinv[row] = 1.0f / st;
  }
}

// ------------------------------------------------------------------
// K3a/K3b: column softmax stats (axis=1, over p)
// ------------------------------------------------------------------
__global__ __launch_bounds__(256) void k_colpart(
    const float* __restrict__ U, float* __restrict__ pm, float* __restrict__ ps) {
  int q = blockIdx.x * 256 + threadIdx.x;
  int pc = blockIdx.y;
  int b = blockIdx.z;
  const float* u = U + ((size_t)b * SS + pc * 128) * SS + q;
  float m = -INFINITY, s = 0.f;
  for (int p = 0; p < 128; ++p) {
    float x = u[(size_t)p * SS];
    float nm = fmaxf(m, x);
    s = s * __expf(m - nm) + __expf(x - nm);
    m = nm;
  }
  int o = (pc * BB + b) * SS + q;
  pm[o] = m;
  ps[o] = s;
}

__global__ __launch_bounds__(256) void k_colcomb(
    const float* __restrict__ pm, const float* __restrict__ ps,
    float* __restrict__ colmax, float* __restrict__ colinv) {
  int i = blockIdx.x * 256 + threadIdx.x;
  float m = -INFINITY;
#pragma unroll
  for (int pc = 0; pc < 16; ++pc) m = fmaxf(m, pm[(size_t)pc * BB * SS + i]);
  float s = 0.f;
#pragma unroll
  for (int pc = 0; pc < 16; ++pc)
    s += ps[(size_t)pc * BB * SS + i] * __expf(pm[(size_t)pc * BB * SS + i] - m);
  colmax[i] = m;
  colinv[i] = 1.0f / s;
}

// ------------------------------------------------------------------
// MFMA level kernels: Out[r,h] = sum_k exp(U - max) * E[k,h]
// (unchanged from round 6 — HW-validated)
// ------------------------------------------------------------------
template <int LEVEL>
__global__ __launch_bounds__(512, 4) void k_level(
    const float* __restrict__ U,
    const ushort_t* __restrict__ B0h, const ushort_t* __restrict__ B0l,
    const ushort_t* __restrict__ B1h, const ushort_t* __restrict__ B1l,
    const float* __restrict__ rowmax, const float* __restrict__ rowinv,
    const float* __restrict__ colmax, const float* __restrict__ colinv,
    const float* __restrict__ Eq, const float* __restrict__ Ep,
    float* __restrict__ A1w, float* __restrict__ B1w,
    float* __restrict__ out) {
  __shared__ ushort_t Ph[32 * 64];    // 4 KB
  __shared__ ushort_t Pl[32 * 64];    // 4 KB
  __shared__ ushort_t Bsh[256 * 64];  // 32 KB
  __shared__ ushort_t Bsl[256 * 64];  // 32 KB
  int b = blockIdx.z;
  int mode = blockIdx.y;
  int r0 = blockIdx.x << 5;
  int tid = threadIdx.x;
  size_t bS = (size_t)b * SS;
  const float* Ub = U + bS * SS;
  const ushort_t* Bh = (mode == 0 ? B0h : B1h) + (size_t)b * HH * SS;
  const ushort_t* Bl = (mode == 0 ? B0l : B1l) + (size_t)b * HH * SS;

  int srow0 = tid >> 4;           // mode0: p row 0..31
  int sc40 = (tid & 15) << 2;     // mode0: q (k) 0..60
  int srow1 = tid >> 3;           // mode1: p (k) 0..63
  int sc41 = (tid & 7) << 2;      // mode1: q col 0..28
  float rm = 0.f;
  float4 cm4;
  if (mode == 0) rm = rowmax[bS + r0 + srow0];
  else cm4 = *(const float4*)(colmax + bS + r0 + sc41);

  int w = tid >> 6, l = tid & 63;
  int wr = w >> 2, wc = w & 3;
  int arow = wr * 16 + (l & 15);
  unsigned asw = ((unsigned)(arow & 7)) << 4;
  int lk8 = (l >> 4) << 3;
  int hcol = wc * 64 + (l & 15);

  f32x4 acc[4];
#pragma unroll
  for (int i = 0; i < 4; ++i) acc[i] = (f32x4){0.f, 0.f, 0.f, 0.f};

  char* PhB = (char*)Ph;
  char* PlB = (char*)Pl;
  char* BhB = (char*)Bsh;
  char* BlB = (char*)Bsl;

  for (int k0 = 0; k0 < SS; k0 += 64) {
#pragma unroll
    for (int i = 0; i < 4; ++i) {
      int idx = tid + i * 512;
      int h = idx >> 3;
      int k8 = (idx & 7) << 3;
      unsigned off = ((unsigned)(h * 128 + k8 * 2)) ^ (((unsigned)(h & 7)) << 4);
      *(ushort8*)(BhB + off) = *(const ushort8*)(Bh + (size_t)h * SS + k0 + k8);
      *(ushort8*)(BlB + off) = *(const ushort8*)(Bl + (size_t)h * SS + k0 + k8);
    }
    if (mode == 0) {
      float4 u4 = *(const float4*)(Ub + (size_t)(r0 + srow0) * SS + k0 + sc40);
      ushort4 h4, l4;
      ushort_t hh, ll;
      bsplit(__expf(u4.x - rm), hh, ll); h4.x = hh; l4.x = ll;
      bsplit(__expf(u4.y - rm), hh, ll); h4.y = hh; l4.y = ll;
      bsplit(__expf(u4.z - rm), hh, ll); h4.z = hh; l4.z = ll;
      bsplit(__expf(u4.w - rm), hh, ll); h4.w = hh; l4.w = ll;
      unsigned off = ((unsigned)(srow0 * 128 + sc40 * 2)) ^ (((unsigned)(srow0 & 7)) << 4);
      *(ushort4*)(PhB + off) = h4;
      *(ushort4*)(PlB + off) = l4;
    } else {
      float4 u4 = *(const float4*)(Ub + (size_t)(k0 + srow1) * SS + r0 + sc41);
      float e[4] = {__expf(u4.x - cm4.x), __expf(u4.y - cm4.y),
                    __expf(u4.z - cm4.z), __expf(u4.w - cm4.w)};
#pragma unroll
      for (int j = 0; j < 4; ++j) {
        ushort_t hh, ll;
        bsplit(e[j], hh, ll);
        int rr = sc41 + j;
        unsigned off = ((unsigned)(rr * 128 + srow1 * 2)) ^ (((unsigned)(rr & 7)) << 4);
        *(ushort_t*)(PhB + off) = hh;
        *(ushort_t*)(PlB + off) = ll;
      }
    }
    __syncthreads();
#pragma unroll
    for (int kc = 0; kc < 64; kc += 32) {
      int ak = kc + lk8;
      unsigned aoff = ((unsigned)(arow * 128 + ak * 2)) ^ asw;
      bf16x8 ah = *(const bf16x8*)(PhB + aoff);
      bf16x8 al = *(const bf16x8*)(PlB + aoff);
#pragma unroll
      for (int cf = 0; cf < 4; ++cf) {
        int h = hcol + cf * 16;
        unsigned boff = ((unsigned)(h * 128 + ak * 2)) ^ (((unsigned)(h & 7)) << 4);
        bf16x8 bh = *(const bf16x8*)(BhB + boff);
        bf16x8 bl = *(const bf16x8*)(BlB + boff);
        acc[cf] = __builtin_amdgcn_mfma_f32_16x16x32_bf16(ah, bh, acc[cf], 0, 0, 0);
        acc[cf] = __builtin_amdgcn_mfma_f32_16x16x32_bf16(ah, bl, acc[cf], 0, 0, 0);
        acc[cf] = __builtin_amdgcn_mfma_f32_16x16x32_bf16(al, bh, acc[cf], 0, 0, 0);
      }
    }
    __syncthreads();
  }

  int crow = wr * 16 + ((l >> 4) << 2);
  if (LEVEL == 1) {
    const float* inv = mode == 0 ? rowinv : colinv;
    float* Out = mode == 0 ? A1w : B1w;
#pragma unroll
    for (int j = 0; j < 4; ++j) {
      int rr = r0 + crow + j;
      float sc = inv[bS + rr];
#pragma unroll
      for (int cf = 0; cf < 4; ++cf) {
        int h = hcol + cf * 16;
        Out[(bS + rr) * HH + h] = acc[cf][j] * sc;
      }
    }
  } else {
    if (mode == 0) {
      float* Gqp = out + GSEG;
#pragma unroll
      for (int j = 0; j < 4; ++j) {
        int rr = r0 + crow + j;
        float sc = rowinv[bS + rr];
#pragma unroll
        for (int cf = 0; cf < 4; ++cf) {
          int h = hcol + cf * 16;
          size_t eidx = (bS + rr) * HH + h;
          float a2 = acc[cf][j] * sc;
          float ep = Ep[eidx];
          float a1 = A1w[eidx];
          float* g = Gqp + (bS + rr) * (size_t)(5 * HH) + h;
          g[0 * HH] = ep;
          g[1 * HH] = a1;
          g[2 * HH] = a2;
          g[3 * HH] = ep * a1;
          g[4 * HH] = ep * a2;
        }
      }
    } else {
#pragma unroll
      for (int j = 0; j < 4; ++j) {
        int rr = r0 + crow + j;
        float sc = colinv[bS + rr];
#pragma unroll
        for (int cf = 0; cf < 4; ++cf) {
          int h = hcol + cf * 16;
          size_t eidx = (bS + rr) * HH + h;
          float b2 = acc[cf][j] * sc;
          float eq = Eq[eidx];
          float b1 = B1w[eidx];
          float* g = out + (bS + rr) * (size_t)(5 * HH) + h;
          g[0 * HH] = eq;
          g[1 * HH] = b1;
          g[2 * HH] = b2;
          g[3 * HH] = eq * b1;
          g[4 * HH] = eq * b2;
        }
      }
    }
  }
}

// ------------------------------------------------------------------
extern "C" void kernel_launch(void* const* d_in, const int* in_sizes, int n_in,
                              void* d_out, int out_size, void* d_ws, size_t ws_size,
                              hipStream_t stream) {
  const float* Eq = (const float*)d_in[0];
  const float* Ep = (const float*)d_in[1];
  const float* m1 = (const float*)d_in[2];
  const float* m2 = (const float*)d_in[3];
  const float* W  = (const float*)d_in[4];
  float* out = (float*)d_out;

  // workspace layout (~96 MB — matches the HW-proven round-3/6 footprint)
  float* ws     = (float*)d_ws;
  float* U      = ws;                              // B*S*S fp32 (64 MB)
  float* rowmax = U + (size_t)BB * SS * SS;
  float* rowinv = rowmax + BB * SS;
  float* colmax = rowinv + BB * SS;
  float* colinv = colmax + BB * SS;
  float* spv    = colinv + BB * SS;
  float* sqv    = spv + BB * SS;
  float* A1w    = sqv + BB * SS;                   // B*S*H fp32 (8 MB)
  float* B1w    = A1w + NT;                        // B*S*H fp32 (8 MB)
  ushort_t* EqTh = (ushort_t*)(B1w + NT);          // 4 x (B*H*S) bf16 (16 MB)
  ushort_t* EqTl = EqTh + NT;
  ushort_t* EpTh = EqTl + NT;
  ushort_t* EpTl = EpTh + NT;
  // Row-major split tensors alias A1w/B1w: consumed only by k_trim, which
  // runs before anything writes A1w/B1w. EqRh+EqRl (8MB) == A1w's 8MB.
  ushort_t* EqRh = (ushort_t*)A1w;
  ushort_t* EqRl = EqRh + NT;
  ushort_t* ApRh = (ushort_t*)B1w;
  ushort_t* ApRl = ApRh + NT;
  // pm/ps also alias A1w: written by k_colpart AFTER k_trim (EqR dead),
  // dead after k_colcomb, before k_level<1> writes A1w.
  float* pm     = A1w;
  float* ps     = pm + 16 * BB * SS;
  // A1T/B1T alias EqT/EpT storage: EqT/EpT dead after k_level<1>
  ushort_t* A1Th = EqTh;
  ushort_t* A1Tl = EqTl;
  ushort_t* B1Th = EpTh;
  ushort_t* B1Tl = EpTl;

  dim3 tcg(SS / 64, HH / 64, BB);

  k_rowdots<<<2 * BB * SS / 4, 256, 0, stream>>>(Eq, Ep, W, sqv, spv);
  k_rc<<<(int)(NT / 2048), 256, 0, stream>>>(Eq, nullptr, EqRh, EqRl);
  k_rc<<<(int)(NT / 2048), 256, 0, stream>>>(Ep, W + 2 * HH, ApRh, ApRl);
  k_tc<<<tcg, 256, 0, stream>>>(Eq, EqTh, EqTl);
  k_tc<<<tcg, 256, 0, stream>>>(Ep, EpTh, EpTl);
  k_trim<<<dim3(SS / 256, SS / 32, BB), 512, 0, stream>>>(
      ApRh, ApRl, EqRh, EqRl, m1, m2, spv, sqv, U);
  k_rowstats<<<BB * SS, 256, 0, stream>>>(U, rowmax, rowinv);
  k_colpart<<<dim3(SS / 256, 16, BB), 256, 0, stream>>>(U, pm, ps);
  k_colcomb<<<BB * SS / 256, 256, 0, stream>>>(pm, ps, colmax, colinv);
  k_level<1><<<dim3(SS / 32, 2, BB), 512, 0, stream>>>(
      U, EqTh, EqTl, EpTh, EpTl, rowmax, rowinv, colmax, colinv,
      Eq, Ep, A1w, B1w, out);
  k_tc<<<tcg, 256, 0, stream>>>(A1w, A1Th, A1Tl);
  k_tc<<<tcg, 256, 0, stream>>>(B1w, B1Th, B1Tl);
  k_level<2><<<dim3(SS / 32, 2, BB), 512, 0, stream>>>(
      U, B1Th, B1Tl, A1Th, A1Tl, rowmax, rowinv, colmax, colinv,
      Eq, Ep, A1w, B1w, out);
}